// Round 2
// baseline (112.967 us; speedup 1.0000x reference)
//
#include <hip/hip_runtime.h>

#define N 2048
#define IN_DIM 32
#define L 64
#define LDSH 72  // LDS row stride in halves: 144 B/row, 16B-aligned, 2-way-bank-alias only (free)

typedef _Float16 half_t;
typedef _Float16 h2 __attribute__((ext_vector_type(2)));
typedef _Float16 h8 __attribute__((ext_vector_type(8)));
union H8 { h8 v; h2 h[4]; };

__device__ inline h2 habs2(h2 a) {
    unsigned u; __builtin_memcpy(&u, &a, 4);
    u &= 0x7FFF7FFFu;
    __builtin_memcpy(&a, &u, 4);
    return a;
}

__device__ inline float dot2acc(h2 a, h2 b, float c) {
#if __has_builtin(__builtin_amdgcn_fdot2)
    return __builtin_amdgcn_fdot2(a, b, c, false);
#else
    return c + (float)a.x * (float)b.x + (float)a.y * (float)b.y;
#endif
}

// ---------------------------------------------------------------------------
// Kernel A: per-node precompute (fp32 math, f16 outputs for the edge tiles).
//   z    = lrelu(x @ W_ne + b_ne)
//   zi   = z @ W_e1a                  -> stored f16 [N,64]
//   zjb  = z @ W_e1b + b_e1           -> stored f16 [N,64]
//   A[i] = 0.505 * sum_l w2[l]*zi[i,l]          (fp32)
//   B[j] = 0.505 * sum_l w2[l]*zjb[j,l] + b_e2  (fp32)
//   w2p  = 0.495 * w2                 -> stored f16
// One wave per row; lane l owns column l.
// ---------------------------------------------------------------------------
__global__ __launch_bounds__(64) void precompute_kernel(
    const float* __restrict__ x,
    const float* __restrict__ W_ne,
    const float* __restrict__ b_ne,
    const float* __restrict__ W_e1a,
    const float* __restrict__ W_e1b,
    const float* __restrict__ b_e1,
    const float* __restrict__ w_e2,
    const float* __restrict__ b_e2,
    half_t* __restrict__ zi_h,
    half_t* __restrict__ zjb_h,
    float* __restrict__ A_g,
    float* __restrict__ B_g,
    half_t* __restrict__ w2p_h)
{
    const int i = blockIdx.x;
    const int l = threadIdx.x;
    __shared__ float zrow[L];

    float acc = b_ne[l];
    #pragma unroll
    for (int k = 0; k < IN_DIM; ++k)
        acc = fmaf(x[i * IN_DIM + k], W_ne[k * L + l], acc);   // x row wave-uniform -> s_load
    float z = fmaxf(acc, 0.01f * acc);
    zrow[l] = z;
    __syncthreads();

    float vi = 0.0f, vj = b_e1[l];
    #pragma unroll 8
    for (int m = 0; m < L; ++m) {
        float zm = zrow[m];
        vi = fmaf(zm, W_e1a[m * L + l], vi);
        vj = fmaf(zm, W_e1b[m * L + l], vj);
    }
    zi_h[i * L + l]  = (half_t)vi;
    zjb_h[i * L + l] = (half_t)vj;

    float w = w_e2[l];
    float ta = w * vi, tb = w * vj;
    #pragma unroll
    for (int off = 32; off > 0; off >>= 1) {
        ta += __shfl_xor(ta, off);
        tb += __shfl_xor(tb, off);
    }
    if (l == 0) {
        A_g[i] = 0.505f * ta;
        B_g[i] = 0.505f * tb + b_e2[0];
    }
    if (i == 0) w2p_h[l] = (half_t)(0.495f * w);
}

// ---------------------------------------------------------------------------
// Kernel B: N x N edge map, f16 packed inner loop with fp32 (v_dot2) accum.
//   logit[i,j] = A[i] + B[j] + sum_l w2p[l] * |zi[i,l] + zjb[j,l]|
//   out[i,j]   = (sigmoid(logit) + 1e-8) * exp(gumbel[i,j])
// 64x64 tile / 256-thread block, 4x4 micro-tile, strided mapping
// (i = ty+16*ri, j = tx+16*rj): zjb reads 2-way-aliased (free), zi broadcast.
// ---------------------------------------------------------------------------
__global__ __launch_bounds__(256) void edge_kernel(
    const half_t* __restrict__ zi_h,
    const half_t* __restrict__ zjb_h,
    const float* __restrict__ A_g,
    const float* __restrict__ B_g,
    const half_t* __restrict__ w2p_h,
    const float* __restrict__ gumbel,
    float* __restrict__ out)
{
    __shared__ half_t zi_s[64 * LDSH];   // 9216 B
    __shared__ half_t zj_s[64 * LDSH];   // 9216 B

    const int jb = blockIdx.x * 64;
    const int ib = blockIdx.y * 64;
    const int t  = threadIdx.x;
    const int tx = t & 15;
    const int ty = t >> 4;

    // Stage 64x64 f16 tiles (8 KB each) as 16B chunks: 512 chunks/tile, 2 reps.
    #pragma unroll
    for (int rep = 0; rep < 2; ++rep) {
        int idx = rep * 256 + t;
        int row = idx >> 3;
        int c   = idx & 7;
        *(float4*)&zi_s[row * LDSH + c * 8] = *(const float4*)&zi_h[(ib + row) * L + c * 8];
        *(float4*)&zj_s[row * LDSH + c * 8] = *(const float4*)&zjb_h[(jb + row) * L + c * 8];
    }
    __syncthreads();

    float acc[4][4];
    #pragma unroll
    for (int a = 0; a < 4; ++a)
        #pragma unroll
        for (int b = 0; b < 4; ++b) acc[a][b] = 0.0f;

    #pragma unroll
    for (int lq = 0; lq < 8; ++lq) {          // 8 l-values per iteration
        H8 w;
        w.v = *(const h8*)&w2p_h[lq * 8];     // wave-uniform -> scalar load
        H8 ai[4], bj[4];
        #pragma unroll
        for (int r = 0; r < 4; ++r) {
            ai[r].v = *(const h8*)&zi_s[(ty + 16 * r) * LDSH + lq * 8];
            bj[r].v = *(const h8*)&zj_s[(tx + 16 * r) * LDSH + lq * 8];
        }
        #pragma unroll
        for (int ri = 0; ri < 4; ++ri)
            #pragma unroll
            for (int rj = 0; rj < 4; ++rj) {
                float a0 = acc[ri][rj];
                #pragma unroll
                for (int c = 0; c < 4; ++c) {
                    h2 s = ai[ri].h[c] + bj[rj].h[c];     // v_pk_add_f16
                    a0 = dot2acc(habs2(s), w.h[c], a0);   // v_and_b32 + v_dot2_f32_f16
                }
                acc[ri][rj] = a0;
            }
    }

    float Ai[4], Bj[4];
    #pragma unroll
    for (int r = 0; r < 4; ++r) {
        Ai[r] = A_g[ib + ty + 16 * r];
        Bj[r] = B_g[jb + tx + 16 * r];
    }

    #pragma unroll
    for (int ri = 0; ri < 4; ++ri) {
        int gi = ib + ty + 16 * ri;
        #pragma unroll
        for (int rj = 0; rj < 4; ++rj) {
            int gj = jb + tx + 16 * rj;
            float logit = Ai[ri] + Bj[rj] + acc[ri][rj];
            float p = 1.0f / (1.0f + __expf(-logit));
            float g = gumbel[(size_t)gi * N + gj];
            out[(size_t)gi * N + gj] = (p + 1e-8f) * __expf(g);  // exp(log(p+1e-8)+g)
        }
    }
}

extern "C" void kernel_launch(void* const* d_in, const int* in_sizes, int n_in,
                              void* d_out, int out_size, void* d_ws, size_t ws_size,
                              hipStream_t stream) {
    const float* x      = (const float*)d_in[0];
    // d_in[1] = in_adj — unused by the reference computation
    const float* gumbel = (const float*)d_in[2];
    const float* W_ne   = (const float*)d_in[3];
    const float* b_ne   = (const float*)d_in[4];
    const float* W_e1a  = (const float*)d_in[5];
    const float* W_e1b  = (const float*)d_in[6];
    const float* b_e1   = (const float*)d_in[7];
    const float* w_e2   = (const float*)d_in[8];
    const float* b_e2   = (const float*)d_in[9];
    float* out = (float*)d_out;

    char* ws = (char*)d_ws;
    half_t* zi_h  = (half_t*)(ws);                           // 256 KB
    half_t* zjb_h = (half_t*)(ws + 256 * 1024);              // 256 KB
    float*  A_g   = (float*)(ws + 512 * 1024);               // 8 KB
    float*  B_g   = (float*)(ws + 512 * 1024 + 8 * 1024);    // 8 KB
    half_t* w2p_h = (half_t*)(ws + 512 * 1024 + 16 * 1024);  // 128 B

    precompute_kernel<<<N, 64, 0, stream>>>(x, W_ne, b_ne, W_e1a, W_e1b, b_e1,
                                            w_e2, b_e2, zi_h, zjb_h, A_g, B_g, w2p_h);
    edge_kernel<<<dim3(N / 64, N / 64), 256, 0, stream>>>(zi_h, zjb_h, A_g, B_g,
                                                          w2p_h, gumbel, out);
}

// Round 4
// 112.146 us; speedup vs baseline: 1.0073x; 1.0073x over previous
//
#include <hip/hip_runtime.h>

#define N 2048
#define IN_DIM 32
#define L 64
#define LDSH 72  // LDS row stride in halves: 144 B/row, 16B-aligned, 2-way-bank-alias only (free)

typedef _Float16 half_t;
typedef _Float16 h2 __attribute__((ext_vector_type(2)));
typedef _Float16 h8 __attribute__((ext_vector_type(8)));
union H8 { h8 v; h2 h[4]; };

__device__ inline h2 habs2(h2 a) {
    unsigned u; __builtin_memcpy(&u, &a, 4);
    u &= 0x7FFF7FFFu;
    __builtin_memcpy(&a, &u, 4);
    return a;
}

__device__ inline float dot2acc(h2 a, h2 b, float c) {
#if __has_builtin(__builtin_amdgcn_fdot2)
    return __builtin_amdgcn_fdot2(a, b, c, false);
#else
    return c + (float)a.x * (float)b.x + (float)a.y * (float)b.y;
#endif
}

// ---------------------------------------------------------------------------
// Kernel A: per-node precompute (fp32 math, f16 outputs for the edge tiles).
//   z    = lrelu(x @ W_ne + b_ne)
//   zi   = z @ W_e1a                  -> stored f16 [N,64]
//   zjb  = z @ W_e1b + b_e1           -> stored f16 [N,64]
//   A[i] = 0.505 * sum_l w2[l]*zi[i,l]          (fp32)
//   B[j] = 0.505 * sum_l w2[l]*zjb[j,l] + b_e2  (fp32)
//   w2p  = 0.495 * w2                 -> stored f16
// 256-thread blocks, one wave per row (4 rows/block); waves are independent.
// __shfl broadcast of z (lane-const -> v_readlane, SGPR fma operand).
// ---------------------------------------------------------------------------
__global__ __launch_bounds__(256) void precompute_kernel(
    const float* __restrict__ x,
    const float* __restrict__ W_ne,
    const float* __restrict__ b_ne,
    const float* __restrict__ W_e1a,
    const float* __restrict__ W_e1b,
    const float* __restrict__ b_e1,
    const float* __restrict__ w_e2,
    const float* __restrict__ b_e2,
    half_t* __restrict__ zi_h,
    half_t* __restrict__ zjb_h,
    float* __restrict__ A_g,
    float* __restrict__ B_g,
    half_t* __restrict__ w2p_h)
{
    const int l = threadIdx.x & 63;
    const int i = blockIdx.x * 4 + (threadIdx.x >> 6);

    float acc = b_ne[l];
    #pragma unroll
    for (int k = 0; k < IN_DIM; ++k)
        acc = fmaf(x[i * IN_DIM + k], W_ne[k * L + l], acc);   // x row wave-uniform -> s_load
    float z = fmaxf(acc, 0.01f * acc);

    float vi = 0.0f, vj = b_e1[l];
    #pragma unroll
    for (int m = 0; m < L; ++m) {
        float zm = __shfl(z, m);                 // lane-const -> readlane (SGPR operand)
        vi = fmaf(zm, W_e1a[m * L + l], vi);
        vj = fmaf(zm, W_e1b[m * L + l], vj);
    }
    zi_h[i * L + l]  = (half_t)vi;
    zjb_h[i * L + l] = (half_t)vj;

    float w = w_e2[l];
    float ta = w * vi, tb = w * vj;
    #pragma unroll
    for (int off = 32; off > 0; off >>= 1) {
        ta += __shfl_xor(ta, off);
        tb += __shfl_xor(tb, off);
    }
    if (l == 0) {
        A_g[i] = 0.505f * ta;
        B_g[i] = 0.505f * tb + b_e2[0];
    }
    if (i == 0) w2p_h[l] = (half_t)(0.495f * w);
}

// ---------------------------------------------------------------------------
// Kernel B: N x N edge map, f16 packed inner loop with fp32 (v_dot2) accum.
//   logit[i,j] = A[i] + B[j] + sum_l w2p[l] * |zi[i,l] + zjb[j,l]|
//   out[i,j]   = (sigmoid(logit) + 1e-8) * exp(gumbel[i,j])
// 64x64 tile / 256-thread block, 4x4 micro-tile, strided mapping
// (i = ty+16*ri, j = tx+16*rj): zjb reads 2-way-aliased (free), zi broadcast.
// ---------------------------------------------------------------------------
__global__ __launch_bounds__(256) void edge_kernel(
    const half_t* __restrict__ zi_h,
    const half_t* __restrict__ zjb_h,
    const float* __restrict__ A_g,
    const float* __restrict__ B_g,
    const half_t* __restrict__ w2p_h,
    const float* __restrict__ gumbel,
    float* __restrict__ out)
{
    __shared__ half_t zi_s[64 * LDSH];   // 9216 B
    __shared__ half_t zj_s[64 * LDSH];   // 9216 B

    const int jb = blockIdx.x * 64;
    const int ib = blockIdx.y * 64;
    const int t  = threadIdx.x;
    const int tx = t & 15;
    const int ty = t >> 4;

    // Stage 64x64 f16 tiles (8 KB each) as 16B chunks: 512 chunks/tile, 2 reps.
    #pragma unroll
    for (int rep = 0; rep < 2; ++rep) {
        int idx = rep * 256 + t;
        int row = idx >> 3;
        int c   = idx & 7;
        *(float4*)&zi_s[row * LDSH + c * 8] = *(const float4*)&zi_h[(ib + row) * L + c * 8];
        *(float4*)&zj_s[row * LDSH + c * 8] = *(const float4*)&zjb_h[(jb + row) * L + c * 8];
    }
    __syncthreads();

    float acc[4][4];
    #pragma unroll
    for (int a = 0; a < 4; ++a)
        #pragma unroll
        for (int b = 0; b < 4; ++b) acc[a][b] = 0.0f;

    #pragma unroll
    for (int lq = 0; lq < 8; ++lq) {          // 8 l-values per iteration
        H8 w;
        w.v = *(const h8*)&w2p_h[lq * 8];     // wave-uniform -> scalar load
        H8 ai[4], bj[4];
        #pragma unroll
        for (int r = 0; r < 4; ++r) {
            ai[r].v = *(const h8*)&zi_s[(ty + 16 * r) * LDSH + lq * 8];
            bj[r].v = *(const h8*)&zj_s[(tx + 16 * r) * LDSH + lq * 8];
        }
        #pragma unroll
        for (int ri = 0; ri < 4; ++ri)
            #pragma unroll
            for (int rj = 0; rj < 4; ++rj) {
                float a0 = acc[ri][rj];
                #pragma unroll
                for (int c = 0; c < 4; ++c) {
                    h2 s = ai[ri].h[c] + bj[rj].h[c];     // v_pk_add_f16
                    a0 = dot2acc(habs2(s), w.h[c], a0);   // v_and_b32 + v_dot2_f32_f16
                }
                acc[ri][rj] = a0;
            }
    }

    float Ai[4], Bj[4];
    #pragma unroll
    for (int r = 0; r < 4; ++r) {
        Ai[r] = A_g[ib + ty + 16 * r];
        Bj[r] = B_g[jb + tx + 16 * r];
    }

    #pragma unroll
    for (int ri = 0; ri < 4; ++ri) {
        int gi = ib + ty + 16 * ri;
        #pragma unroll
        for (int rj = 0; rj < 4; ++rj) {
            int gj = jb + tx + 16 * rj;
            float logit = Ai[ri] + Bj[rj] + acc[ri][rj];
            float p = 1.0f / (1.0f + __expf(-logit));
            float g = gumbel[(size_t)gi * N + gj];
            out[(size_t)gi * N + gj] = (p + 1e-8f) * __expf(g);  // exp(log(p+1e-8)+g)
        }
    }
}

extern "C" void kernel_launch(void* const* d_in, const int* in_sizes, int n_in,
                              void* d_out, int out_size, void* d_ws, size_t ws_size,
                              hipStream_t stream) {
    const float* x      = (const float*)d_in[0];
    // d_in[1] = in_adj — unused by the reference computation
    const float* gumbel = (const float*)d_in[2];
    const float* W_ne   = (const float*)d_in[3];
    const float* b_ne   = (const float*)d_in[4];
    const float* W_e1a  = (const float*)d_in[5];
    const float* W_e1b  = (const float*)d_in[6];
    const float* b_e1   = (const float*)d_in[7];
    const float* w_e2   = (const float*)d_in[8];
    const float* b_e2   = (const float*)d_in[9];
    float* out = (float*)d_out;

    char* ws = (char*)d_ws;
    half_t* zi_h  = (half_t*)(ws);                           // 256 KB
    half_t* zjb_h = (half_t*)(ws + 256 * 1024);              // 256 KB
    float*  A_g   = (float*)(ws + 512 * 1024);               // 8 KB
    float*  B_g   = (float*)(ws + 512 * 1024 + 8 * 1024);    // 8 KB
    half_t* w2p_h = (half_t*)(ws + 512 * 1024 + 16 * 1024);  // 128 B

    precompute_kernel<<<N / 4, 256, 0, stream>>>(x, W_ne, b_ne, W_e1a, W_e1b, b_e1,
                                                 w_e2, b_e2, zi_h, zjb_h, A_g, B_g, w2p_h);
    edge_kernel<<<dim3(N / 64, N / 64), 256, 0, stream>>>(zi_h, zjb_h, A_g, B_g,
                                                          w2p_h, gumbel, out);
}